// Round 4
// baseline (295.561 us; speedup 1.0000x reference)
//
#include <hip/hip_runtime.h>
#include <stdint.h>

#define BB 64
#define PP 24656
#define CC 81
#define NEGPOS 3
#define RPT 16                     // rows per tile (one tile per wave)
#define TB (RPT * CC * 4)          // 5184 bytes = 5*1024 + 64
#define TFLT (RPT * CC)            // 1296 floats
#define NT ((BB * PP) / RPT)       // 98624 tiles exactly
#define TPB (PP / RPT)             // 1541 tiles per batch row exactly
#define NSLOT 256
#define NBLK 768                   // 3 blocks/CU * 256 CU

typedef unsigned int u32;
typedef unsigned long long u64;

__device__ __forceinline__ void gload_lds16(const void* g, void* l) {
    __builtin_amdgcn_global_load_lds(
        (const __attribute__((address_space(1))) u32*)g,
        (__attribute__((address_space(3))) u32*)l, 16, 0, 0);
}
__device__ __forceinline__ void gload_lds4(const void* g, void* l) {
    __builtin_amdgcn_global_load_lds(
        (const __attribute__((address_space(1))) u32*)g,
        (__attribute__((address_space(3))) u32*)l, 4, 0, 0);
}

__global__ __launch_bounds__(256, 3) void k_main(
    const float* __restrict__ loc_data,
    const float* __restrict__ conf_data,
    const float* __restrict__ occ_data,
    const float* __restrict__ loc_t,
    const int*   __restrict__ conf_t,
    const float* __restrict__ occ_t,
    double* __restrict__ acc,     // NSLOT*3
    int* __restrict__ num_pos,    // 64
    float* __restrict__ mine)     // BB*PP
{
    // per-wave double-buffered slice: [wave][buf][1296 floats]
    __shared__ __align__(16) float tile[4][2][TFLT];   // 41472 B
    __shared__ double red[4][3];

    const int t = threadIdx.x;
    const int w = t >> 6;
    const int lane = t & 63;
    const int r = lane >> 2;        // row within tile 0..15
    const int s = lane & 3;         // quarter-row segment
    const int wave_id = blockIdx.x * 4 + w;
    const int n_waves = NBLK * 4;

    double a_l = 0.0, a_o = 0.0, a_cp = 0.0;

    // prologue: stage first tile into buf 0
    {
        const char* gb = (const char*)conf_data + (long)wave_id * TB;
        char* wl = (char*)tile[w][0];
        #pragma unroll
        for (int c = 0; c < 5; ++c)
            gload_lds16(gb + (c << 10) + (lane << 4), wl + (c << 10));
        if (lane < 16)
            gload_lds4(gb + 5120 + (lane << 2), wl + 5120);
    }

    int cur = 0;
    for (int td = wave_id; td < NT; td += n_waves) {
        const int tdn = td + n_waves;
        if (tdn < NT) {
            // prefetch next tile into the other buffer (6 VMEM ops)
            const char* gb = (const char*)conf_data + (long)tdn * TB;
            char* wl = (char*)tile[w][cur ^ 1];
            #pragma unroll
            for (int c = 0; c < 5; ++c)
                gload_lds16(gb + (c << 10) + (lane << 4), wl + (c << 10));
            if (lane < 16)
                gload_lds4(gb + 5120 + (lane << 2), wl + 5120);
            // drain everything EXCEPT the 6 just-issued prefetch ops:
            // current tile (issued last iter) is older -> guaranteed complete
            asm volatile("s_waitcnt vmcnt(6)" ::: "memory");
        } else {
            asm volatile("s_waitcnt vmcnt(0)" ::: "memory");
        }

        const float* rp = tile[w][cur] + r * CC;
        const int start = (s == 0) ? 0 : (s * 20 + 1);   // 21|20|20|20 split
        float sum = (s == 0) ? __expf(rp[20]) : 0.0f;
        #pragma unroll
        for (int j = 0; j < 20; ++j) sum += __expf(rp[start + j]);
        sum += __shfl_xor(sum, 1, 64);
        sum += __shfl_xor(sum, 2, 64);   // all 4 lanes of a row hold the row sum

        bool pos = false;
        const long i = (long)td * RPT + r;
        if (s == 0) {
            const int tc = conf_t[i];
            const float cat = rp[tc];
            const float diff = __logf(sum) - cat;   // lse - conf_at_t, >= 0
            pos = tc > 0;
            if (pos) {
                a_cp += (double)diff;
                const float4 ld4 = *(const float4*)(loc_data + i * 4);
                const float4 lt4 = *(const float4*)(loc_t + i * 4);
                float sl = 0.0f;
                { float d = ld4.x - lt4.x, ad = fabsf(d); sl += (ad < 1.f) ? 0.5f*d*d : ad - 0.5f; }
                { float d = ld4.y - lt4.y, ad = fabsf(d); sl += (ad < 1.f) ? 0.5f*d*d : ad - 0.5f; }
                { float d = ld4.z - lt4.z, ad = fabsf(d); sl += (ad < 1.f) ? 0.5f*d*d : ad - 0.5f; }
                { float d = ld4.w - lt4.w, ad = fabsf(d); sl += (ad < 1.f) ? 0.5f*d*d : ad - 0.5f; }
                a_l += (double)sl;
                const float ot = occ_t[i];
                if (ot != -1.0f) { const float dd = occ_data[i] - ot; a_o += (double)(dd * dd); }
                mine[i] = 0.0f;
            } else {
                mine[i] = fmaxf(diff, 0.0f);
            }
        }
        const u64 bal = __ballot(pos);
        if (bal != 0ull && lane == 0)
            atomicAdd(&num_pos[td / TPB], (int)__popcll(bal));

        cur ^= 1;
    }

    #pragma unroll
    for (int sft = 1; sft < 64; sft <<= 1) {
        a_l  += __shfl_xor(a_l,  sft, 64);
        a_o  += __shfl_xor(a_o,  sft, 64);
        a_cp += __shfl_xor(a_cp, sft, 64);
    }
    if (lane == 0) { red[w][0] = a_l; red[w][1] = a_o; red[w][2] = a_cp; }
    __syncthreads();
    if (t == 0) {
        double x0 = red[0][0] + red[1][0] + red[2][0] + red[3][0];
        double x1 = red[0][1] + red[1][1] + red[2][1] + red[3][1];
        double x2 = red[0][2] + red[1][2] + red[2][2] + red[3][2];
        const int slot = blockIdx.x & (NSLOT - 1);
        atomicAdd(&acc[slot * 3 + 0], x0);
        atomicAdd(&acc[slot * 3 + 1], x1);
        atomicAdd(&acc[slot * 3 + 2], x2);
    }
}

// One block per batch row; values register-resident; histogram via
// ballot-match aggregation (1 atomic per equal-bin group per wave).
__global__ __launch_bounds__(1024) void k_select(
    const float* __restrict__ mine,
    const int* __restrict__ num_pos,
    double* __restrict__ csel)
{
    __shared__ u32 hist[256];
    __shared__ u32 sh_prefix, sh_kk;
    __shared__ double dred[16];
    __shared__ u32 cred[16];

    const int b = blockIdx.x;
    const int t = threadIdx.x;
    const int w = t >> 6;
    const int lane = t & 63;
    const float* row = mine + (long)b * PP;

    u32 u[25];
    #pragma unroll
    for (int r = 0; r < 25; ++r) {
        const int idx = t + (r << 10);
        u[r] = (idx < PP) ? __float_as_uint(row[idx]) : 0u;  // +0.0 pads sort last
    }

    const int np = num_pos[b];
    int k = NEGPOS * np;
    if (k > PP - 1) k = PP - 1;
    if (k <= 0) return;   // uniform across block

    u32 prefix = 0, mask = 0, kk = (u32)k;

    for (int pass = 0; pass < 4; ++pass) {
        const int shift = 24 - 8 * pass;
        if (t < 256) hist[t] = 0;
        __syncthreads();
        #pragma unroll
        for (int r = 0; r < 25; ++r) {
            const u32 uu = u[r];
            const bool valid = (uu & mask) == prefix;
            const u32 bin = (uu >> shift) & 255u;
            u64 eq = __ballot(valid);
            #pragma unroll
            for (int bi = 0; bi < 8; ++bi) {
                const u64 bal = __ballot((bin >> bi) & 1u);
                eq &= ((bin >> bi) & 1u) ? bal : ~bal;
            }
            if (valid && ((int)__ffsll(eq) - 1 == lane))
                atomicAdd(&hist[bin], (u32)__popcll(eq));
        }
        __syncthreads();
        if (t < 256) {
            u32 above = 0;
            for (int bb = t + 1; bb < 256; ++bb) above += hist[bb];
            if (above < kk && above + hist[t] >= kk) {   // exactly one bin
                sh_prefix = prefix | ((u32)t << shift);
                sh_kk = kk - above;
            }
        }
        __syncthreads();
        prefix = sh_prefix;
        kk = sh_kk;
        mask |= (0xFFu << shift);
        __syncthreads();
    }

    const u32 thr_bits = prefix;
    const float thr = __uint_as_float(thr_bits);

    double ssum = 0.0;
    u32 cnt = 0;
    #pragma unroll
    for (int r = 0; r < 25; ++r) {
        const u32 uu = u[r];
        if (uu > thr_bits) { ssum += (double)__uint_as_float(uu); cnt++; }
    }
    #pragma unroll
    for (int sft = 1; sft < 64; sft <<= 1) {
        ssum += __shfl_xor(ssum, sft, 64);
        cnt  += __shfl_xor(cnt,  sft, 64);
    }
    if (lane == 0) { dred[w] = ssum; cred[w] = cnt; }
    __syncthreads();
    if (t == 0) {
        double S = 0.0; u32 cg = 0;
        #pragma unroll
        for (int j = 0; j < 16; ++j) { S += dred[j]; cg += cred[j]; }
        S += (double)(k - (int)cg) * (double)thr;   // ties at threshold value
        atomicAdd(csel, S);
    }
}

__global__ __launch_bounds__(256) void k_final(
    const double* __restrict__ acc,
    const double* __restrict__ csel,
    const int* __restrict__ num_pos,
    float* __restrict__ out)
{
    __shared__ double red[4][4];
    const int t = threadIdx.x;
    const int w = t >> 6;
    const int lane = t & 63;

    double l = acc[t * 3 + 0];
    double o = acc[t * 3 + 1];
    double c = acc[t * 3 + 2];
    double npd = (t < BB) ? (double)num_pos[t] : 0.0;
    #pragma unroll
    for (int sft = 1; sft < 64; sft <<= 1) {
        l   += __shfl_xor(l,   sft, 64);
        o   += __shfl_xor(o,   sft, 64);
        c   += __shfl_xor(c,   sft, 64);
        npd += __shfl_xor(npd, sft, 64);
    }
    if (lane == 0) { red[w][0] = l; red[w][1] = o; red[w][2] = c; red[w][3] = npd; }
    __syncthreads();
    if (t == 0) {
        double L = 0, O = 0, Cp = 0, N = 0;
        #pragma unroll
        for (int j = 0; j < 4; ++j) { L += red[j][0]; O += red[j][1]; Cp += red[j][2]; N += red[j][3]; }
        out[0] = (float)(L / N);
        out[1] = (float)((Cp + csel[0]) / N);
        out[2] = (float)(O / N);
    }
}

extern "C" void kernel_launch(void* const* d_in, const int* in_sizes, int n_in,
                              void* d_out, int out_size, void* d_ws, size_t ws_size,
                              hipStream_t stream) {
    const float* loc_data  = (const float*)d_in[0];
    const float* conf_data = (const float*)d_in[1];
    const float* occ_data  = (const float*)d_in[2];
    const float* loc_t     = (const float*)d_in[3];
    const int*   conf_t    = (const int*)d_in[4];
    const float* occ_t     = (const float*)d_in[5];

    char* ws = (char*)d_ws;
    double* csel   = (double*)ws;            // 1 double
    int*    numpos = (int*)(ws + 64);        // 64 ints
    double* acc    = (double*)(ws + 512);    // NSLOT*3 doubles
    float*  mine   = (float*)(ws + 8192);    // BB*PP floats

    hipMemsetAsync(ws, 0, 8192, stream);

    k_main<<<NBLK, 256, 0, stream>>>(loc_data, conf_data, occ_data, loc_t,
                                     conf_t, occ_t, acc, numpos, mine);
    k_select<<<BB, 1024, 0, stream>>>(mine, numpos, csel);
    k_final<<<1, 256, 0, stream>>>(acc, csel, numpos, (float*)d_out);
}